// Round 12
// baseline (117.593 us; speedup 1.0000x reference)
//
#include <hip/hip_runtime.h>
#include <hip/hip_bf16.h>
#include <stdint.h>

// AutoregressiveDense: B=8192, D=1024, STRIDE=16, OUT=64, L=64
#define BROWS 8192
#define DDIM  1024
#define LDIM  64
#define ODIM  64
#define NDIM  4096
#define KSTRIDE 16

typedef __attribute__((ext_vector_type(8))) short bf16x8;           // MFMA A/B frag
typedef __attribute__((ext_vector_type(4))) float f32x4;            // MFMA C/D frag
typedef __attribute__((ext_vector_type(8))) unsigned short u16x8;   // 16B bf16 store

static __device__ __forceinline__ unsigned short f2bf(float f) {
    union { float f; uint32_t u; } v; v.f = f;
    uint32_t r = 0x7FFFu + ((v.u >> 16) & 1u);
    return (unsigned short)((v.u + r) >> 16);
}

static __device__ __forceinline__ void async16(const void* g, void* l) {
    __builtin_amdgcn_global_load_lds(
        (const __attribute__((address_space(1))) void*)g,
        (__attribute__((address_space(3))) void*)l, 16, 0, 0);
}

// ---------- merged prep: blocks [0,1024) build masked W' (B^T bf16), blocks [1024,5120) convert x ----------
__global__ __launch_bounds__(256) void prep_kernel(const float* __restrict__ x,
                                                   const float* __restrict__ W,
                                                   unsigned short* __restrict__ xb,
                                                   unsigned short* __restrict__ wbt) {
    const int bid = blockIdx.x;
    if (bid < 1024) {
        // W [L][D][O] f32 -> masked bf16 W' [N=l*64+o][K=d], zero for d >= l*16
        __shared__ float tile[64][65];
        const int l  = bid >> 4;
        const int d0 = (bid & 15) << 6;
        const int t  = threadIdx.x;
        {
            const int dd = t >> 2;
            const int o4 = (t & 3) << 4;
            const float* src = W + ((size_t)((l << 10) + d0 + dd) << 6) + o4;
            #pragma unroll
            for (int j = 0; j < 4; ++j) {
                float4 v = reinterpret_cast<const float4*>(src)[j];
                tile[dd][o4 + 4 * j + 0] = v.x;
                tile[dd][o4 + 4 * j + 1] = v.y;
                tile[dd][o4 + 4 * j + 2] = v.z;
                tile[dd][o4 + 4 * j + 3] = v.w;
            }
        }
        __syncthreads();
        {
            const int o    = t >> 2;
            const int dloc = (t & 3) << 4;
            const int kmax = l * KSTRIDE;
            unsigned short* dst = wbt + ((size_t)((l << 6) + o) << 10) + d0 + dloc;
            u16x8 r0, r1;
            #pragma unroll
            for (int j = 0; j < 8; ++j) {
                int da = d0 + dloc + j;
                int db = da + 8;
                r0[j] = (da < kmax) ? f2bf(tile[dloc + j][o])     : (unsigned short)0;
                r1[j] = (db < kmax) ? f2bf(tile[dloc + 8 + j][o]) : (unsigned short)0;
            }
            *reinterpret_cast<u16x8*>(dst)     = r0;
            *reinterpret_cast<u16x8*>(dst + 8) = r1;
        }
    } else {
        int i = (bid - 1024) * 256 + threadIdx.x;
        const float4* xf = reinterpret_cast<const float4*>(x);
        float4 v0 = xf[2 * i];
        float4 v1 = xf[2 * i + 1];
        u16x8 r;
        r[0] = f2bf(v0.x); r[1] = f2bf(v0.y); r[2] = f2bf(v0.z); r[3] = f2bf(v0.w);
        r[4] = f2bf(v1.x); r[5] = f2bf(v1.y); r[6] = f2bf(v1.z); r[7] = f2bf(v1.w);
        reinterpret_cast<u16x8*>(xb)[i] = r;
    }
}

// ---------- main GEMM: 128x128 tile, BK=32, 4 waves (2Mx2N, wave tile 64x64) ----------
// r11 bug: stageA passed a tid*32 LDS dest to global_load_lds — but the HW dest is
// WAVE-UNIFORM BASE + lane*16 (m104/m108), so half of A never landed -> NaN. Fixed by
// two contiguous 4KB regions, each dest = base + tid*16 (async#1 rows 0-63, granule
// tid -> row tid>>2 chunk tid&3; async#2 rows 64-127 at +4096), sources re-mapped.
// Theory under test (r10): cut LDS traffic 2.7x by loading B global->register directly
// (per-lane dwordx4; B panel 256KB L2-resident, reused by 64 bm-blocks), reg dbuf dist-1;
// only A through LDS (DMA dist-2, 3 bufs). 3 independent blocks/CU ((256,3)) for TLP.
#define ITER(T, BC, BN) do { \
    stageA((T) + 2);                                   /* buf[(T-1)%3]; readers drained */ \
    loadB((T) + 1, BN);                                /* reg loads, used next iter */ \
    const char* pb_ = lds + ((T) % 3) * 8192; \
    bf16x8 a[4]; \
    _Pragma("unroll") \
    for (int m = 0; m < 4; ++m) a[m] = *reinterpret_cast<const bf16x8*>(pb_ + aoff + m * 1024); \
    __builtin_amdgcn_s_setprio(1); \
    _Pragma("unroll") \
    for (int m = 0; m < 4; ++m) \
        _Pragma("unroll") \
        for (int n = 0; n < 4; ++n) \
            acc[m][n] = __builtin_amdgcn_mfma_f32_16x16x32_bf16(a[m], BC[n], acc[m][n], 0, 0, 0); \
    __builtin_amdgcn_s_setprio(0); \
    asm volatile("s_waitcnt lgkmcnt(0)" ::: "memory"); /* A frag reads drained (WAR) */ \
    asm volatile("s_waitcnt vmcnt(6)" ::: "memory");   /* A(T+1) landed; A(T+2),B(T+1) fly */ \
    __builtin_amdgcn_sched_barrier(0); \
    __builtin_amdgcn_s_barrier(); \
    __builtin_amdgcn_sched_barrier(0); \
} while (0)

__global__ __launch_bounds__(256, 3) void ar_gemm_kernel(
        const unsigned short* __restrict__ xb,
        const unsigned short* __restrict__ wbt,
        const float* __restrict__ bias,
        float* __restrict__ out) {
    __shared__ char lds[24576];   // 3 bufs x A[128][64B], linear

    const int s  = blockIdx.x >> 8;            // 8 supertiles of 256 blocks (one generation each)
    const int i  = blockIdx.x & 255;
    const int bm = ((s & 3) << 4) + (i & 15);          // 0..63 (tiles of 128 rows)
    const int bn = ((s < 4) ? 16 : 0) + 15 - (i >> 4); // heavy bn (16..31) first, big nkt first
    const int tid  = threadIdx.x;
    const int lane = tid & 63;
    const int wid  = tid >> 6;
    const int wm   = wid >> 1;                 // 2 M-waves x 2 N-waves, wave tile 64x64
    const int wn   = wid & 1;

    const int nkt = bn + 1;                    // K-tiles of 32

    // A staging sources: async#1 -> granule tid (row tid>>2, chunk tid&3, rows 0-63);
    // async#2 -> granule 256+tid (rows 64-127). LDS dest = base + tid*16 (HW lane rule).
    const char* gA1 = (const char*)xb + ((size_t)((bm << 7) + (tid >> 2)) << 11) + ((tid & 3) << 4);
    const char* gA2 = gA1 + ((size_t)64 << 11);
    // B frag gather pointers: row = bn*128 + wn*64 + 16n + (lane&15); 16B granule lane>>4
    const char* gB[4];
    #pragma unroll
    for (int n = 0; n < 4; ++n)
        gB[n] = (const char*)wbt + ((size_t)((bn << 7) + (wn << 6) + (n << 4) + (lane & 15)) << 11)
              + ((lane >> 4) << 4);
    // A frag read offset: row = wm*64 + 16m + (lane&15), granule lane>>4 (conflict-free)
    const int aoff = ((wm << 6) + (lane & 15)) * 64 + ((lane >> 4) << 4);

    f32x4 acc[4][4];
    #pragma unroll
    for (int m = 0; m < 4; ++m)
        #pragma unroll
        for (int n = 0; n < 4; ++n)
            acc[m][n] = (f32x4)(0.f);

    auto stageA = [&](int t) {                 // 2 asyncs into buf t%3; dest = base + tid*16
        const int kb = (t < nkt ? t : nkt - 1) << 6;
        char* l = lds + (t % 3) * 8192 + tid * 16;
        async16(gA1 + kb, l);
        async16(gA2 + kb, l + 4096);
    };
    auto loadB = [&](int t, bf16x8 (&b)[4]) {  // 4 reg gathers; clamp source
        const int kb = (t < nkt ? t : nkt - 1) << 6;
        #pragma unroll
        for (int n = 0; n < 4; ++n)
            b[n] = *reinterpret_cast<const bf16x8*>(gB[n] + kb);
    };

    bf16x8 b0[4], b1[4];
    stageA(0); stageA(1);                      // 4 VM
    loadB(0, b0);                              // 4 VM
    asm volatile("s_waitcnt vmcnt(6)" ::: "memory");   // A(0) landed; A(1),B(0) in flight
    __builtin_amdgcn_s_barrier();

    int t = 0;
    while (true) {
        ITER(t, b0, b1);
        if (++t >= nkt) break;
        ITER(t, b1, b0);
        if (++t >= nkt) break;
    }
    asm volatile("s_waitcnt vmcnt(0)" ::: "memory");   // drain clamped tails

    // epilogue: C/D layout col=lane&15, row=(lane>>4)*4+j; add bias in f32
    const int crow = (bm << 7) + (wm << 6) + ((lane >> 4) << 2);
    const int ccol = (bn << 7) + (wn << 6) + (lane & 15);
    float bv[4];
    #pragma unroll
    for (int n = 0; n < 4; ++n) bv[n] = bias[ccol + n * 16];
    #pragma unroll
    for (int m = 0; m < 4; ++m)
        #pragma unroll
        for (int n = 0; n < 4; ++n)
            #pragma unroll
            for (int j = 0; j < 4; ++j)
                out[(size_t)(crow + m * 16 + j) * NDIM + ccol + n * 16] = acc[m][n][j] + bv[n];
}

// ---------- fallback: naive f32 (used only if workspace too small) ----------
__global__ __launch_bounds__(256) void naive_kernel(const float* __restrict__ x,
                                                    const float* __restrict__ W,
                                                    const float* __restrict__ bias,
                                                    float* __restrict__ out) {
    size_t idx = (size_t)blockIdx.x * 256 + threadIdx.x;
    if (idx >= (size_t)BROWS * NDIM) return;
    int m = (int)(idx >> 12);
    int n = (int)(idx & 4095);
    int l = n >> 6;
    int o = n & 63;
    int kmax = l * KSTRIDE;
    float s = bias[n];
    const float* xr = x + (size_t)m * DDIM;
    const float* wp = W + ((size_t)l << 16) + o;
    for (int d = 0; d < kmax; ++d) s += xr[d] * wp[(size_t)d << 6];
    out[idx] = s;
}

extern "C" void kernel_launch(void* const* d_in, const int* in_sizes, int n_in,
                              void* d_out, int out_size, void* d_ws, size_t ws_size,
                              hipStream_t stream) {
    const float* x = (const float*)d_in[0];
    const float* W = (const float*)d_in[1];
    const float* b = (const float*)d_in[2];
    float* out = (float*)d_out;

    const size_t need = ((size_t)BROWS * DDIM + (size_t)NDIM * DDIM) * sizeof(unsigned short);
    if (ws_size < need) {
        int total = BROWS * NDIM;
        naive_kernel<<<(total + 255) / 256, 256, 0, stream>>>(x, W, b, out);
        return;
    }
    unsigned short* xbuf = (unsigned short*)d_ws;             // bf16 x  [8192][1024]
    unsigned short* wbt  = xbuf + (size_t)BROWS * DDIM;       // bf16 W' [4096][1024]

    prep_kernel<<<5120, 256, 0, stream>>>(x, W, xbuf, wbt);
    ar_gemm_kernel<<<2048, 256, 0, stream>>>(xbuf, wbt, b, out);
}

// Round 14
// 75.320 us; speedup vs baseline: 1.5612x; 1.5612x over previous
//
#include <hip/hip_runtime.h>
#include <hip/hip_bf16.h>
#include <stdint.h>

// AutoregressiveDense: B=8192, D=1024, STRIDE=16, OUT=64, L=64
#define BROWS 8192
#define DDIM  1024
#define LDIM  64
#define ODIM  64
#define NDIM  4096
#define KSTRIDE 16

typedef __attribute__((ext_vector_type(8))) short bf16x8;           // MFMA A/B frag
typedef __attribute__((ext_vector_type(4))) float f32x4;            // MFMA C/D frag
typedef __attribute__((ext_vector_type(8))) unsigned short u16x8;   // 16B bf16 store

static __device__ __forceinline__ unsigned short f2bf(float f) {
    union { float f; uint32_t u; } v; v.f = f;
    uint32_t r = 0x7FFFu + ((v.u >> 16) & 1u);
    return (unsigned short)((v.u + r) >> 16);
}

static __device__ __forceinline__ void async16(const void* g, void* l) {
    __builtin_amdgcn_global_load_lds(
        (const __attribute__((address_space(1))) void*)g,
        (__attribute__((address_space(3))) void*)l, 16, 0, 0);
}

// ---------- prep: masked W' (B^T bf16) only — x conversion is fused into the GEMM ----------
__global__ __launch_bounds__(256) void prep_kernel(const float* __restrict__ W,
                                                   unsigned short* __restrict__ wbt) {
    __shared__ float tile[64][65];
    const int bid = blockIdx.x;
    const int l  = bid >> 4;
    const int d0 = (bid & 15) << 6;
    const int t  = threadIdx.x;
    {
        const int dd = t >> 2;
        const int o4 = (t & 3) << 4;
        const float* src = W + ((size_t)((l << 10) + d0 + dd) << 6) + o4;
        #pragma unroll
        for (int j = 0; j < 4; ++j) {
            float4 v = reinterpret_cast<const float4*>(src)[j];
            tile[dd][o4 + 4 * j + 0] = v.x;
            tile[dd][o4 + 4 * j + 1] = v.y;
            tile[dd][o4 + 4 * j + 2] = v.z;
            tile[dd][o4 + 4 * j + 3] = v.w;
        }
    }
    __syncthreads();
    {
        const int o    = t >> 2;
        const int dloc = (t & 3) << 4;
        const int kmax = l * KSTRIDE;
        unsigned short* dst = wbt + ((size_t)((l << 6) + o) << 10) + d0 + dloc;
        u16x8 r0, r1;
        #pragma unroll
        for (int j = 0; j < 8; ++j) {
            int da = d0 + dloc + j;
            int db = da + 8;
            r0[j] = (da < kmax) ? f2bf(tile[dloc + j][o])     : (unsigned short)0;
            r1[j] = (db < kmax) ? f2bf(tile[dloc + 8 + j][o]) : (unsigned short)0;
        }
        *reinterpret_cast<u16x8*>(dst)     = r0;
        *reinterpret_cast<u16x8*>(dst + 8) = r1;
    }
}

// ---------- main GEMM: r7 structure (256x128, BK=32, 8 waves, dist-2 triple-buffer) ----------
// + fused x f32->bf16 A-staging. r13 bug (fixed): stageB had TWO asyncs/thread ported from
// a 256-thread kernel — with 512 threads it read B rows 128-191 (OOB) and overflowed the
// 8KB B region into the next buffer's A data (absmax 0.55). Now ONE async/thread
// (512 x 16B = exactly the 8KB B tile), same as working r7/r9.
// A-write bank swizzle (enumeration-verified, 8 distinct 16B-start groups per 8 lanes on
// writes AND reads): chunk c of row r at r*64 + ((c + ((r>>1)&1))&3)*16; frag reads use
// chunk ((lane>>4) + ((lane>>1)&1))&3 (constant per lane). Removes r9's ds_write conflict.
// vmcnt: per iter 1 stageB + 4 loadA. End-of-iter vmcnt(5) = drains stageB(t+1)+loadA(t+1)
// (B(t+1) landed before barrier), allows current-iter 5 prefetches in flight. Prologue
// vmcnt(4) = drains stageB(0),stageB(1),loadA(0); allows loadA(1).
__global__ __launch_bounds__(512, 2) void ar_gemm_kernel(
        const float* __restrict__ x,
        const unsigned short* __restrict__ wbt,
        const float* __restrict__ bias,
        float* __restrict__ out) {
    __shared__ char lds[73728];   // buf p at p*24576: A[256 rows][64B] (swizzled) + B[128][64B] at +16384

    const int s  = blockIdx.x >> 8;            // 4 supertiles of 256 blocks (one generation each)
    const int i  = blockIdx.x & 255;
    const int bm = ((s & 1) << 4) + (i & 15);          // 0..31 (tiles of 256 rows)
    const int bn = ((s < 2) ? 16 : 0) + 15 - (i >> 4); // heavy bn (16..31) first, big nkt first
    const int tid  = threadIdx.x;
    const int lane = tid & 63;
    const int wid  = tid >> 6;
    const int wm   = wid >> 1;                 // 4 M-waves x 2 N-waves, wave tile 64x64
    const int wn   = wid & 1;

    const int nkt = bn + 1;                    // K-tiles of 32

    // fused A staging: thread -> row rA = tid>>1, half hA = tid&1 (16 f32 -> 2 swizzled 16B chunks)
    const int rA = tid >> 1, hA = tid & 1;
    const float* gAf = x + ((size_t)((bm << 8) + rA) << 10) + (hA << 4);
    const int qA   = (rA >> 1) & 1;
    const int pc0  = (((2 * hA)     + qA) & 3) << 4;   // LDS chunk position of chunk 2h
    const int pc1  = (((2 * hA + 1) + qA) & 3) << 4;   // and of chunk 2h+1
    const int arow = rA * 64;

    // B staging (DMA, linear): ONE granule per thread: row tid>>2 (0..127), chunk tid&3
    const char* gB = (const char*)wbt + ((size_t)((bn << 7) + (tid >> 2)) << 11) + ((tid & 3) << 4);

    // frag read offsets: A uses the swizzled chunk, B is linear (both at 8-lane/start floor)
    const int aoff = ((wm << 6) + (lane & 15)) * 64 + ((((lane >> 4) + ((lane >> 1) & 1)) & 3) << 4);
    const int boff = 16384 + ((wn << 6) + (lane & 15)) * 64 + ((lane >> 4) << 4);

    f32x4 acc[4][4];
    #pragma unroll
    for (int m = 0; m < 4; ++m)
        #pragma unroll
        for (int n = 0; n < 4; ++n)
            acc[m][n] = (f32x4)(0.f);

    auto stageB = [&](int t) {                 // 1 async into buf t%3 B-region; clamp source
        const int kb = (t < nkt ? t : nkt - 1) << 6;
        async16(gB + kb, lds + (t % 3) * 24576 + 16384 + tid * 16);
    };
    auto loadA = [&](int t, float4* r) {       // 4x dwordx4 f32; clamp source
        const float* g = gAf + ((size_t)(t < nkt ? t : nkt - 1) << 5);
        #pragma unroll
        for (int j = 0; j < 4; ++j)
            r[j] = reinterpret_cast<const float4*>(g)[j];
    };
    auto cvtwA = [&](int t, const float4* r) { // 8 cvt_pk + 2 swizzled ds_write_b128
        char* base = lds + (t % 3) * 24576 + arow;
        const float* f = reinterpret_cast<const float*>(r);
        int d[4];
        #pragma unroll
        for (int j = 0; j < 4; ++j)
            asm("v_cvt_pk_bf16_f32 %0, %1, %2" : "=v"(d[j]) : "v"(f[2 * j]), "v"(f[2 * j + 1]));
        *reinterpret_cast<int4*>(base + pc0) = make_int4(d[0], d[1], d[2], d[3]);
        #pragma unroll
        for (int j = 0; j < 4; ++j)
            asm("v_cvt_pk_bf16_f32 %0, %1, %2" : "=v"(d[j]) : "v"(f[8 + 2 * j]), "v"(f[9 + 2 * j]));
        *reinterpret_cast<int4*>(base + pc1) = make_int4(d[0], d[1], d[2], d[3]);
    };

    // prologue: B(0),B(1) DMA; A(0)->regs->LDS; A(1)->regs (consumed iter 0)
    float4 a0[4], ar[4];
    stageB(0); stageB(1);
    loadA(0, a0);
    loadA(1, ar);
    cvtwA(0, a0);                              // implicit wait drains loadA(0) (and stageB(0,1))
    asm volatile("s_waitcnt lgkmcnt(0)" ::: "memory");
    asm volatile("s_waitcnt vmcnt(4)" ::: "memory");   // B(0) landed; loadA(1) may fly
    __builtin_amdgcn_sched_barrier(0);
    __builtin_amdgcn_s_barrier();
    __builtin_amdgcn_sched_barrier(0);

    for (int t = 0; t < nkt; ++t) {
        stageB(t + 2);                         // buf (t-1)%3 B: readers drained at iter t-1
        cvtwA(t + 1, ar);                      // buf (t+1)%3 A; implicit wait drains loadA(t+1)
        loadA(t + 2, ar);                      // refill after cvt consumed ar (reg WAR via compiler)
        const char* pb = lds + (t % 3) * 24576;
        bf16x8 a[4], bb[2];
        #pragma unroll
        for (int m = 0; m < 4; ++m)
            a[m] = *reinterpret_cast<const bf16x8*>(pb + aoff + m * 1024);
        __builtin_amdgcn_s_setprio(1);
        bb[0] = *reinterpret_cast<const bf16x8*>(pb + boff);
        bb[1] = *reinterpret_cast<const bf16x8*>(pb + boff + 1024);
        #pragma unroll
        for (int m = 0; m < 4; ++m)
            #pragma unroll
            for (int n = 0; n < 2; ++n)
                acc[m][n] = __builtin_amdgcn_mfma_f32_16x16x32_bf16(a[m], bb[n], acc[m][n], 0, 0, 0);
        bb[0] = *reinterpret_cast<const bf16x8*>(pb + boff + 2048);
        bb[1] = *reinterpret_cast<const bf16x8*>(pb + boff + 3072);
        #pragma unroll
        for (int m = 0; m < 4; ++m)
            #pragma unroll
            for (int n = 0; n < 2; ++n)
                acc[m][2 + n] = __builtin_amdgcn_mfma_f32_16x16x32_bf16(a[m], bb[n], acc[m][2 + n], 0, 0, 0);
        __builtin_amdgcn_s_setprio(0);
        asm volatile("s_waitcnt lgkmcnt(0)" ::: "memory"); // frag reads + A ds_writes drained
        asm volatile("s_waitcnt vmcnt(5)" ::: "memory");   // B(t+1)+A(t+1) landed; 5 current fly
        __builtin_amdgcn_sched_barrier(0);
        __builtin_amdgcn_s_barrier();
        __builtin_amdgcn_sched_barrier(0);
    }
    asm volatile("s_waitcnt vmcnt(0)" ::: "memory");       // drain clamped tails

    // epilogue: C/D layout col=lane&15, row=(lane>>4)*4+j; add bias in f32
    const int crow = (bm << 8) + (wm << 6) + ((lane >> 4) << 2);
    const int ccol = (bn << 7) + (wn << 6) + (lane & 15);
    float bv[4];
    #pragma unroll
    for (int n = 0; n < 4; ++n) bv[n] = bias[ccol + n * 16];
    #pragma unroll
    for (int m = 0; m < 4; ++m)
        #pragma unroll
        for (int n = 0; n < 4; ++n)
            #pragma unroll
            for (int j = 0; j < 4; ++j)
                out[(size_t)(crow + m * 16 + j) * NDIM + ccol + n * 16] = acc[m][n][j] + bv[n];
}

// ---------- fallback: naive f32 (used only if workspace too small) ----------
__global__ __launch_bounds__(256) void naive_kernel(const float* __restrict__ x,
                                                    const float* __restrict__ W,
                                                    const float* __restrict__ bias,
                                                    float* __restrict__ out) {
    size_t idx = (size_t)blockIdx.x * 256 + threadIdx.x;
    if (idx >= (size_t)BROWS * NDIM) return;
    int m = (int)(idx >> 12);
    int n = (int)(idx & 4095);
    int l = n >> 6;
    int o = n & 63;
    int kmax = l * KSTRIDE;
    float s = bias[n];
    const float* xr = x + (size_t)m * DDIM;
    const float* wp = W + ((size_t)l << 16) + o;
    for (int d = 0; d < kmax; ++d) s += xr[d] * wp[(size_t)d << 6];
    out[idx] = s;
}

extern "C" void kernel_launch(void* const* d_in, const int* in_sizes, int n_in,
                              void* d_out, int out_size, void* d_ws, size_t ws_size,
                              hipStream_t stream) {
    const float* x = (const float*)d_in[0];
    const float* W = (const float*)d_in[1];
    const float* b = (const float*)d_in[2];
    float* out = (float*)d_out;

    const size_t need = (size_t)NDIM * DDIM * sizeof(unsigned short);   // 8.4 MB
    if (ws_size < need) {
        int total = BROWS * NDIM;
        naive_kernel<<<(total + 255) / 256, 256, 0, stream>>>(x, W, b, out);
        return;
    }
    unsigned short* wbt = (unsigned short*)d_ws;          // bf16 W' [4096][1024]

    prep_kernel<<<1024, 256, 0, stream>>>(W, wbt);
    ar_gemm_kernel<<<1024, 512, 0, stream>>>(x, wbt, b, out);
}

// Round 15
// 62.913 us; speedup vs baseline: 1.8691x; 1.1972x over previous
//
#include <hip/hip_runtime.h>
#include <hip/hip_bf16.h>
#include <stdint.h>

// AutoregressiveDense: B=8192, D=1024, STRIDE=16, OUT=64, L=64
#define BROWS 8192
#define DDIM  1024
#define LDIM  64
#define ODIM  64
#define NDIM  4096
#define KSTRIDE 16

typedef __attribute__((ext_vector_type(8))) short bf16x8;           // MFMA A/B frag
typedef __attribute__((ext_vector_type(4))) float f32x4;            // MFMA C/D frag
typedef __attribute__((ext_vector_type(8))) unsigned short u16x8;   // 16B bf16 store

static __device__ __forceinline__ unsigned short f2bf(float f) {
    union { float f; uint32_t u; } v; v.f = f;
    uint32_t r = 0x7FFFu + ((v.u >> 16) & 1u);
    return (unsigned short)((v.u + r) >> 16);
}

static __device__ __forceinline__ void async16(const void* g, void* l) {
    __builtin_amdgcn_global_load_lds(
        (const __attribute__((address_space(1))) void*)g,
        (__attribute__((address_space(3))) void*)l, 16, 0, 0);
}

// ---------- merged prep: blocks [0,1024) build masked W' (B^T bf16), blocks [1024,5120) convert x ----------
__global__ __launch_bounds__(256) void prep_kernel(const float* __restrict__ x,
                                                   const float* __restrict__ W,
                                                   unsigned short* __restrict__ xb,
                                                   unsigned short* __restrict__ wbt) {
    const int bid = blockIdx.x;
    if (bid < 1024) {
        __shared__ float tile[64][65];
        const int l  = bid >> 4;
        const int d0 = (bid & 15) << 6;
        const int t  = threadIdx.x;
        {
            const int dd = t >> 2;
            const int o4 = (t & 3) << 4;
            const float* src = W + ((size_t)((l << 10) + d0 + dd) << 6) + o4;
            #pragma unroll
            for (int j = 0; j < 4; ++j) {
                float4 v = reinterpret_cast<const float4*>(src)[j];
                tile[dd][o4 + 4 * j + 0] = v.x;
                tile[dd][o4 + 4 * j + 1] = v.y;
                tile[dd][o4 + 4 * j + 2] = v.z;
                tile[dd][o4 + 4 * j + 3] = v.w;
            }
        }
        __syncthreads();
        {
            const int o    = t >> 2;
            const int dloc = (t & 3) << 4;
            const int kmax = l * KSTRIDE;
            unsigned short* dst = wbt + ((size_t)((l << 6) + o) << 10) + d0 + dloc;
            u16x8 r0, r1;
            #pragma unroll
            for (int j = 0; j < 8; ++j) {
                int da = d0 + dloc + j;
                int db = da + 8;
                r0[j] = (da < kmax) ? f2bf(tile[dloc + j][o])     : (unsigned short)0;
                r1[j] = (db < kmax) ? f2bf(tile[dloc + 8 + j][o]) : (unsigned short)0;
            }
            *reinterpret_cast<u16x8*>(dst)     = r0;
            *reinterpret_cast<u16x8*>(dst + 8) = r1;
        }
    } else {
        int i = (bid - 1024) * 256 + threadIdx.x;
        const float4* xf = reinterpret_cast<const float4*>(x);
        float4 v0 = xf[2 * i];
        float4 v1 = xf[2 * i + 1];
        u16x8 r;
        r[0] = f2bf(v0.x); r[1] = f2bf(v0.y); r[2] = f2bf(v0.z); r[3] = f2bf(v0.w);
        r[4] = f2bf(v1.x); r[5] = f2bf(v1.y); r[6] = f2bf(v1.z); r[7] = f2bf(v1.w);
        reinterpret_cast<u16x8*>(xb)[i] = r;
    }
}

// ---------- main GEMM: 256x128, BK=32, 8 waves (4Mx2N) — r7 base + 2-sub-phase interleave ----------
// r7 (1 barrier/step) = 692 TF-effective = the documented 2-phase structure ceiling (m230/m248).
// The regime-gated lever (T3-lite + T5): split each K-step into two m201-style phases
//   P1: {read a0-3,b0,b1 ; stage(t+2) A-halves ; barrier ; lgkm0 ; setprio1 8xMFMA(n0,1) ; barrier}
//   P2: {read b2,b3      ; stage(t+2) B        ; barrier ; lgkm0 ; setprio1 8xMFMA(n2,3) ; vmcnt(3) ; barrier}
// Counted vmcnt once per iter (never 0 in-loop): 3 asyncs/iter -> vmcnt(3) drains stage(t+1),
// leaves stage(t+2) in flight across the barrier. WAR: each phase's lgkm0 drains that buf's
// readers before the following barrier; stage targets buf[(t-1)%3] whose readers drained at t-1.
// LDS 3x24KB=72KB (2 blocks/CU), acc[4][4]=64 (AGPR), supertile XCD map kept.
__global__ __launch_bounds__(512, 2) void ar_gemm_kernel(
        const unsigned short* __restrict__ xb,
        const unsigned short* __restrict__ wbt,
        const float* __restrict__ bias,
        float* __restrict__ out) {
    __shared__ char lds[73728];   // buf p at p*24576: A[256][64B] at +0, B[128][64B] at +16384

    const int s  = blockIdx.x >> 8;            // 4 supertiles of 256 blocks (one generation each)
    const int i  = blockIdx.x & 255;
    const int bm = ((s & 1) << 4) + (i & 15);          // 0..31 (tiles of 256 rows)
    const int bn = ((s < 2) ? 16 : 0) + 15 - (i >> 4); // heavy bn (16..31) first, big nkt first
    const int tid  = threadIdx.x;
    const int lane = tid & 63;
    const int wid  = tid >> 6;
    const int wm   = wid >> 1;                 // 4 M-waves x 2 N-waves, wave tile 64x64
    const int wn   = wid & 1;

    const int nkt = bn + 1;                    // K-tiles of 32

    // staging: thread t -> row t>>2, 16B chunk t&3; LDS linear t*16 (matches gload_lds lane rule)
    const int cb = (tid & 3) << 4;
    const char* gA = (const char*)xb  + ((size_t)((bm << 8) + (tid >> 2)) << 11) + cb;
    const char* gB = (const char*)wbt + ((size_t)((bn << 7) + (tid >> 2)) << 11) + cb;

    // fragment read offsets (bytes): row = (lane&15), k-granule by lane>>4 (r1-proven layout)
    const int aoff = ((wm << 6) + (lane & 15)) * 64 + ((lane >> 4) << 4);
    const int boff = 16384 + ((wn << 6) + (lane & 15)) * 64 + ((lane >> 4) << 4);

    f32x4 acc[4][4];
    #pragma unroll
    for (int m = 0; m < 4; ++m)
        #pragma unroll
        for (int n = 0; n < 4; ++n)
            acc[m][n] = (f32x4)(0.f);

    auto stageA2 = [&](int t) {                // A halves: 2 asyncs into buf t%3
        const int kb = (t < nkt ? t : nkt - 1) << 6;
        char* l = lds + (t % 3) * 24576 + tid * 16;
        async16(gA + kb, l);
        async16(gA + ((size_t)128 << 11) + kb, l + 8192);
    };
    auto stageB1 = [&](int t) {                // B: 1 async into buf t%3
        const int kb = (t < nkt ? t : nkt - 1) << 6;
        async16(gB + kb, lds + (t % 3) * 24576 + 16384 + tid * 16);
    };

    stageA2(0); stageB1(0);
    stageA2(1); stageB1(1);                    // 6 loads in flight
    asm volatile("s_waitcnt vmcnt(3)" ::: "memory");   // tile0 landed; tile1 in flight
    __builtin_amdgcn_sched_barrier(0);
    __builtin_amdgcn_s_barrier();

    for (int t = 0; t < nkt; ++t) {
        const char* pb = lds + (t % 3) * 24576;
        // ---- P1: a0-3 + b0,b1 ; A-stage ; 8 MFMA (n=0,1) ----
        bf16x8 a[4], b0, b1;
        #pragma unroll
        for (int m = 0; m < 4; ++m)
            a[m] = *reinterpret_cast<const bf16x8*>(pb + aoff + m * 1024);
        b0 = *reinterpret_cast<const bf16x8*>(pb + boff);
        b1 = *reinterpret_cast<const bf16x8*>(pb + boff + 1024);
        stageA2(t + 2);
        __builtin_amdgcn_s_barrier();
        asm volatile("s_waitcnt lgkmcnt(0)" ::: "memory");
        __builtin_amdgcn_sched_barrier(0);
        __builtin_amdgcn_s_setprio(1);
        #pragma unroll
        for (int m = 0; m < 4; ++m) {
            acc[m][0] = __builtin_amdgcn_mfma_f32_16x16x32_bf16(a[m], b0, acc[m][0], 0, 0, 0);
            acc[m][1] = __builtin_amdgcn_mfma_f32_16x16x32_bf16(a[m], b1, acc[m][1], 0, 0, 0);
        }
        __builtin_amdgcn_s_setprio(0);
        __builtin_amdgcn_sched_barrier(0);
        __builtin_amdgcn_s_barrier();
        // ---- P2: b2,b3 ; B-stage ; 8 MFMA (n=2,3) ; counted vmcnt ----
        bf16x8 b2, b3;
        b2 = *reinterpret_cast<const bf16x8*>(pb + boff + 2048);
        b3 = *reinterpret_cast<const bf16x8*>(pb + boff + 3072);
        stageB1(t + 2);
        __builtin_amdgcn_s_barrier();
        asm volatile("s_waitcnt lgkmcnt(0)" ::: "memory");
        __builtin_amdgcn_sched_barrier(0);
        __builtin_amdgcn_s_setprio(1);
        #pragma unroll
        for (int m = 0; m < 4; ++m) {
            acc[m][2] = __builtin_amdgcn_mfma_f32_16x16x32_bf16(a[m], b2, acc[m][2], 0, 0, 0);
            acc[m][3] = __builtin_amdgcn_mfma_f32_16x16x32_bf16(a[m], b3, acc[m][3], 0, 0, 0);
        }
        __builtin_amdgcn_s_setprio(0);
        asm volatile("s_waitcnt vmcnt(3)" ::: "memory");   // tile t+1 landed; t+2 stays in flight
        __builtin_amdgcn_sched_barrier(0);
        __builtin_amdgcn_s_barrier();
    }
    asm volatile("s_waitcnt vmcnt(0)" ::: "memory");       // drain clamped tails

    // epilogue: C/D layout col=lane&15, row=(lane>>4)*4+j; add bias in f32
    const int crow = (bm << 8) + (wm << 6) + ((lane >> 4) << 2);
    const int ccol = (bn << 7) + (wn << 6) + (lane & 15);
    float bv[4];
    #pragma unroll
    for (int n = 0; n < 4; ++n) bv[n] = bias[ccol + n * 16];
    #pragma unroll
    for (int m = 0; m < 4; ++m)
        #pragma unroll
        for (int n = 0; n < 4; ++n)
            #pragma unroll
            for (int j = 0; j < 4; ++j)
                out[(size_t)(crow + m * 16 + j) * NDIM + ccol + n * 16] = acc[m][n][j] + bv[n];
}

// ---------- fallback: naive f32 (used only if workspace too small) ----------
__global__ __launch_bounds__(256) void naive_kernel(const float* __restrict__ x,
                                                    const float* __restrict__ W,
                                                    const float* __restrict__ bias,
                                                    float* __restrict__ out) {
    size_t idx = (size_t)blockIdx.x * 256 + threadIdx.x;
    if (idx >= (size_t)BROWS * NDIM) return;
    int m = (int)(idx >> 12);
    int n = (int)(idx & 4095);
    int l = n >> 6;
    int o = n & 63;
    int kmax = l * KSTRIDE;
    float s = bias[n];
    const float* xr = x + (size_t)m * DDIM;
    const float* wp = W + ((size_t)l << 16) + o;
    for (int d = 0; d < kmax; ++d) s += xr[d] * wp[(size_t)d << 6];
    out[idx] = s;
}

extern "C" void kernel_launch(void* const* d_in, const int* in_sizes, int n_in,
                              void* d_out, int out_size, void* d_ws, size_t ws_size,
                              hipStream_t stream) {
    const float* x = (const float*)d_in[0];
    const float* W = (const float*)d_in[1];
    const float* b = (const float*)d_in[2];
    float* out = (float*)d_out;

    const size_t need = ((size_t)BROWS * DDIM + (size_t)NDIM * DDIM) * sizeof(unsigned short);
    if (ws_size < need) {
        int total = BROWS * NDIM;
        naive_kernel<<<(total + 255) / 256, 256, 0, stream>>>(x, W, b, out);
        return;
    }
    unsigned short* xbuf = (unsigned short*)d_ws;             // bf16 x  [8192][1024]
    unsigned short* wbt  = xbuf + (size_t)BROWS * DDIM;       // bf16 W' [4096][1024]

    prep_kernel<<<5120, 256, 0, stream>>>(x, W, xbuf, wbt);
    ar_gemm_kernel<<<1024, 512, 0, stream>>>(xbuf, wbt, b, out);
}